// Round 1
// baseline (200.609 us; speedup 1.0000x reference)
//
#include <hip/hip_runtime.h>
#include <stdint.h>

#define BATCH 128

// ws byte offsets for flag arrays
#define OFF_FZ0 0
#define OFF_FZ1 (OFF_FZ0 + BATCH * 256)
#define OFF_FZ2 (OFF_FZ1 + BATCH * 256)
#define OFF_FX0 (OFF_FZ2 + BATCH * 256)
#define OFF_FX1 (OFF_FX0 + BATCH * 16)
#define OFF_FX2 (OFF_FX1 + BATCH * 16)

// ---- permutation algebra (unchanged from passing kernel) -------------------
__device__ __forceinline__ int A_of(int o) {
    return ((o & 7) << 3) | (((o >> 3) & 1) << 2) | (((o >> 4) & 1) << 1) | ((o >> 5) & 1);
}
__device__ __forceinline__ int S_of(int o) {
    const unsigned P = (0u) | (6u << 3) | (2u << 6) | (4u << 9) | (3u << 12) |
                       (5u << 15) | (1u << 18) | (7u << 21);
    int s = (int)((P >> (3 * (o >> 3))) & 7u);
    return A_of((s << 3) | (o & 7));
}

__device__ __forceinline__ unsigned flag16(const unsigned char* r, int pos) {
    unsigned f;
    if (pos == 0) {
        f = 0;
#pragma unroll
        for (int w = 0; w < 16; ++w) f ^= r[w];
    } else {
        f = r[0];
        for (int w = 17 - pos; w <= 15; ++w) f ^= r[w];
    }
    return f & 1u;
}

// ---- kernel 1: per-batch syndrome parity flags, 6-way job-parallel ---------
// grid (BATCH, 6); unchanged from the passing kernel.
__global__ __launch_bounds__(256) void k_flags(const int* __restrict__ syn,
                                               unsigned char* __restrict__ ws) {
    int b = blockIdx.x, job = blockIdx.y, t = threadIdx.x;
    int dhi = t >> 4, dlo = t & 15;
    const int* base = syn + (size_t)b * 16384;
    __shared__ unsigned char sp[256];
    __shared__ unsigned char g[16];
    unsigned p = 0;

    if (job == 0) {                       // fz0 from z, parity over d1
        const int* z = base;
#pragma unroll
        for (int d1 = 0; d1 < 16; ++d1) p ^= (unsigned)z[d1 * 256 + t];
        sp[t] = p & 1;
        __syncthreads();
        ws[OFF_FZ0 + b * 256 + t] = (unsigned char)flag16(&sp[dhi * 16], dlo);
    } else if (job == 1) {                // fz1 from z, parity over d2
        const int* z = base;
#pragma unroll
        for (int d2 = 0; d2 < 16; ++d2) p ^= (unsigned)z[dhi * 256 + d2 * 16 + dlo];
        sp[t] = p & 1;
        __syncthreads();
        ws[OFF_FZ1 + b * 256 + t] = (unsigned char)flag16(&sp[dhi * 16], dlo);
    } else if (job == 2) {                // fz2 from z, parity over d3
        const int* z = base;
#pragma unroll
        for (int d3 = 0; d3 < 16; ++d3) p ^= (unsigned)z[dhi * 256 + dlo * 16 + d3];
        sp[t] = p & 1;
        __syncthreads();
        ws[OFF_FZ2 + b * 256 + t] = (unsigned char)flag16(&sp[dhi * 16], dlo);
    } else if (job == 3) {                // fx0 from x0
        const int* x0 = base + 4096;
#pragma unroll
        for (int d1 = 0; d1 < 16; ++d1) p ^= (unsigned)x0[d1 * 256 + t];
        sp[t] = p & 1;                    // t = (d2,d3)
        __syncthreads();
        if (t < 16) {
            unsigned q = 0;
            for (int d2 = 0; d2 < 16; ++d2) q ^= sp[d2 * 16 + t];
            g[(t + 1) & 15] = q & 1;      // roll shift 1
        }
        __syncthreads();
        if (t < 16) ws[OFF_FX0 + b * 16 + t] = (unsigned char)flag16(g, t);
    } else if (job == 4) {                // fx1 from x1
        const int* x1 = base + 8192;
#pragma unroll
        for (int d3 = 0; d3 < 16; ++d3) p ^= (unsigned)x1[dhi * 256 + dlo * 16 + d3];
        sp[t] = p & 1;                    // t = (d1,d2)
        __syncthreads();
        if (t < 16) {
            unsigned q = 0;
            for (int d2 = 0; d2 < 16; ++d2) q ^= sp[t * 16 + d2];
            g[t] = q & 1;
        }
        __syncthreads();
        if (t < 16) ws[OFF_FX1 + b * 16 + t] = (unsigned char)flag16(g, t);
    } else {                              // fx2 from x2
        const int* x2 = base + 12288;
#pragma unroll
        for (int d3 = 0; d3 < 16; ++d3) p ^= (unsigned)x2[dhi * 256 + dlo * 16 + d3];
        sp[t] = p & 1;                    // t = (d1,d2)
        __syncthreads();
        if (t < 16) {
            unsigned q = 0;
            for (int d1 = 0; d1 < 16; ++d1) q ^= sp[d1 * 16 + t];
            g[t] = q & 1;
        }
        __syncthreads();
        if (t < 16) ws[OFF_FX2 + b * 16 + t] = (unsigned char)flag16(g, t);
    }
}

// ---- kernel 2: direct-global streaming with permuted addresses -------------
// The per-site permutation src = T[m][v] is a bijection of 0..63 inside one
// 256 B-aligned site row, so a wave's 64 permuted dword reads touch exactly
// the same 4 cache lines as a linear read — coalescing-equivalent. No LDS
// staging, no barriers in the main loop, ~6.4 KB LDS -> 8 blocks/CU (32
// waves/CU) for latency hiding.
__global__ __launch_bounds__(256) void k_main(const float* __restrict__ x,
                                              const unsigned char* __restrict__ ws,
                                              float* __restrict__ out) {
    __shared__ unsigned char T[4096];         // T[m][v] = source element
    __shared__ unsigned char fz0[256], fz1[256], fz2[256];
    __shared__ unsigned char fx0[16], fx1[16], fx2[16];
    __shared__ unsigned char mArr[256];
    __shared__ unsigned char Ctab[3][64];
    __shared__ float red[256];

    int b  = blockIdx.y;
    int i0 = blockIdx.x;
    int t  = threadIdx.x;
    int w  = t >> 6, v = t & 63;

    const float* xb = x + (((size_t)b * 4096 + (size_t)i0 * 256) << 6);

    fz0[t] = ws[OFF_FZ0 + b * 256 + t];
    fz1[t] = ws[OFF_FZ1 + b * 256 + t];
    fz2[t] = ws[OFF_FZ2 + b * 256 + t];
    if (t < 16) {
        fx0[t] = ws[OFF_FX0 + b * 16 + t];
        fx1[t] = ws[OFF_FX1 + b * 16 + t];
        fx2[t] = ws[OFF_FX2 + b * 16 + t];
    }
    if (t < 192) {
        int ax = t >> 6, o = t & 63;
        int bit = 4 >> ax;
        Ctab[ax][o] = (unsigned char)S_of(S_of(o) ^ bit);
    }
    __syncthreads();                          // flags + Ctab ready

    {   // maskcode per site (j0*16+k0), identical to passing kernel
        int j0 = t >> 4, k0 = t & 15;
        unsigned m = (unsigned)fz0[k0 * 16 + j0]
                   | ((unsigned)fx0[k0] << 1)
                   | ((unsigned)fz1[i0 * 16 + k0] << 2)
                   | ((unsigned)fx1[i0] << 3)
                   | ((unsigned)fz2[j0 * 16 + i0] << 4)
                   | ((unsigned)fx2[j0] << 5);
        mArr[t] = (unsigned char)m;
    }
    for (int idx = t; idx < 4096; idx += 256) {
        int m = idx >> 6, vv = idx & 63;
        int src = vv;
        if (m & 32) src ^= 4;
        if (m & 16) src = Ctab[2][src];
        if (m & 8)  src ^= 2;
        if (m & 4)  src = Ctab[1][src];
        if (m & 2)  src ^= 1;
        if (m & 1)  src = Ctab[0][src];
        T[idx] = (unsigned char)src;
    }
    __syncthreads();                          // T + mArr ready

    // wave w streams sites [w*64, w*64+64); lane v accumulates output elem v.
    const unsigned char* Tv = T + v;
    int sbase = w * 64;
    float acc = 0.f;
#pragma unroll 16
    for (int s = 0; s < 64; ++s) {
        int m   = mArr[sbase + s];            // wave-uniform LDS broadcast
        int src = Tv[m << 6];                 // per-lane byte, same-dword merge
        acc += xb[((sbase + s) << 6) | src];  // permuted dword inside 256 B window
    }

    red[t] = acc;
    __syncthreads();
    if (t < 64) {
        float s4 = red[t] + red[t + 64] + red[t + 128] + red[t + 192];
        atomicAdd(out + b * 64 + t, s4 * (1.0f / 4096.0f));
    }
}

extern "C" void kernel_launch(void* const* d_in, const int* in_sizes, int n_in,
                              void* d_out, int out_size, void* d_ws, size_t ws_size,
                              hipStream_t stream) {
    const float* x   = (const float*)d_in[0];
    const int*   syn = (const int*)d_in[1];
    float* out = (float*)d_out;
    unsigned char* ws = (unsigned char*)d_ws;

    hipMemsetAsync(d_out, 0, (size_t)out_size * sizeof(float), stream);
    k_flags<<<dim3(BATCH, 6), 256, 0, stream>>>(syn, ws);
    k_main<<<dim3(16, BATCH), 256, 0, stream>>>(x, ws, out);
}

// Round 2
// 187.722 us; speedup vs baseline: 1.0687x; 1.0687x over previous
//
#include <hip/hip_runtime.h>
#include <stdint.h>

#define BATCH 128

// ws byte offsets for flag arrays
#define OFF_FZ0 0
#define OFF_FZ1 (OFF_FZ0 + BATCH * 256)
#define OFF_FZ2 (OFF_FZ1 + BATCH * 256)
#define OFF_FX0 (OFF_FZ2 + BATCH * 256)
#define OFF_FX1 (OFF_FX0 + BATCH * 16)
#define OFF_FX2 (OFF_FX1 + BATCH * 16)

// ---- permutation algebra (unchanged from passing kernel) -------------------
__device__ __forceinline__ int A_of(int o) {
    return ((o & 7) << 3) | (((o >> 3) & 1) << 2) | (((o >> 4) & 1) << 1) | ((o >> 5) & 1);
}
__device__ __forceinline__ int S_of(int o) {
    const unsigned P = (0u) | (6u << 3) | (2u << 6) | (4u << 9) | (3u << 12) |
                       (5u << 15) | (1u << 18) | (7u << 21);
    int s = (int)((P >> (3 * (o >> 3))) & 7u);
    return A_of((s << 3) | (o & 7));
}

__device__ __forceinline__ unsigned flag16(const unsigned char* r, int pos) {
    unsigned f;
    if (pos == 0) {
        f = 0;
#pragma unroll
        for (int w = 0; w < 16; ++w) f ^= r[w];
    } else {
        f = r[0];
        for (int w = 17 - pos; w <= 15; ++w) f ^= r[w];
    }
    return f & 1u;
}

// ---- kernel 1: per-batch syndrome parity flags, 6-way job-parallel ---------
// grid (BATCH, 6). Job 0 additionally zeroes this batch's 64 output floats,
// replacing the separate hipMemsetAsync dispatch (k_main's atomics run only
// after this kernel completes, so ordering is guaranteed).
__global__ __launch_bounds__(256) void k_flags(const int* __restrict__ syn,
                                               unsigned char* __restrict__ ws,
                                               float* __restrict__ out) {
    int b = blockIdx.x, job = blockIdx.y, t = threadIdx.x;
    int dhi = t >> 4, dlo = t & 15;
    const int* base = syn + (size_t)b * 16384;
    __shared__ unsigned char sp[256];
    __shared__ unsigned char g[16];
    unsigned p = 0;

    if (job == 0) {                       // fz0 from z, parity over d1 (+ out zero)
        if (t < 64) out[b * 64 + t] = 0.0f;
        const int* z = base;
#pragma unroll
        for (int d1 = 0; d1 < 16; ++d1) p ^= (unsigned)z[d1 * 256 + t];
        sp[t] = p & 1;
        __syncthreads();
        ws[OFF_FZ0 + b * 256 + t] = (unsigned char)flag16(&sp[dhi * 16], dlo);
    } else if (job == 1) {                // fz1 from z, parity over d2
        const int* z = base;
#pragma unroll
        for (int d2 = 0; d2 < 16; ++d2) p ^= (unsigned)z[dhi * 256 + d2 * 16 + dlo];
        sp[t] = p & 1;
        __syncthreads();
        ws[OFF_FZ1 + b * 256 + t] = (unsigned char)flag16(&sp[dhi * 16], dlo);
    } else if (job == 2) {                // fz2 from z, parity over d3
        const int* z = base;
#pragma unroll
        for (int d3 = 0; d3 < 16; ++d3) p ^= (unsigned)z[dhi * 256 + dlo * 16 + d3];
        sp[t] = p & 1;
        __syncthreads();
        ws[OFF_FZ2 + b * 256 + t] = (unsigned char)flag16(&sp[dhi * 16], dlo);
    } else if (job == 3) {                // fx0 from x0
        const int* x0 = base + 4096;
#pragma unroll
        for (int d1 = 0; d1 < 16; ++d1) p ^= (unsigned)x0[d1 * 256 + t];
        sp[t] = p & 1;                    // t = (d2,d3)
        __syncthreads();
        if (t < 16) {
            unsigned q = 0;
            for (int d2 = 0; d2 < 16; ++d2) q ^= sp[d2 * 16 + t];
            g[(t + 1) & 15] = q & 1;      // roll shift 1
        }
        __syncthreads();
        if (t < 16) ws[OFF_FX0 + b * 16 + t] = (unsigned char)flag16(g, t);
    } else if (job == 4) {                // fx1 from x1
        const int* x1 = base + 8192;
#pragma unroll
        for (int d3 = 0; d3 < 16; ++d3) p ^= (unsigned)x1[dhi * 256 + dlo * 16 + d3];
        sp[t] = p & 1;                    // t = (d1,d2)
        __syncthreads();
        if (t < 16) {
            unsigned q = 0;
            for (int d2 = 0; d2 < 16; ++d2) q ^= sp[t * 16 + d2];
            g[t] = q & 1;
        }
        __syncthreads();
        if (t < 16) ws[OFF_FX1 + b * 16 + t] = (unsigned char)flag16(g, t);
    } else {                              // fx2 from x2
        const int* x2 = base + 12288;
#pragma unroll
        for (int d3 = 0; d3 < 16; ++d3) p ^= (unsigned)x2[dhi * 256 + dlo * 16 + d3];
        sp[t] = p & 1;                    // t = (d1,d2)
        __syncthreads();
        if (t < 16) {
            unsigned q = 0;
            for (int d1 = 0; d1 < 16; ++d1) q ^= sp[d1 * 16 + t];
            g[t] = q & 1;
        }
        __syncthreads();
        if (t < 16) ws[OFF_FX2 + b * 16 + t] = (unsigned char)flag16(g, t);
    }
}

// ---- kernel 2: direct-global streaming with permuted addresses -------------
// Permuted per-lane dword reads inside one 256 B-aligned site row touch the
// same 4 cache lines as a linear read. HBM-bound (~128 MiB compulsory read);
// nontemporal loads skip L2/L3 allocation (x has zero reuse). No barriers in
// the main loop; ~6.4 KB LDS -> 8 blocks/CU for latency hiding.
__global__ __launch_bounds__(256) void k_main(const float* __restrict__ x,
                                              const unsigned char* __restrict__ ws,
                                              float* __restrict__ out) {
    __shared__ unsigned char T[4096];         // T[m][v] = source element
    __shared__ unsigned char fz0[256], fz1[256], fz2[256];
    __shared__ unsigned char fx0[16], fx1[16], fx2[16];
    __shared__ unsigned char mArr[256];
    __shared__ unsigned char Ctab[3][64];
    __shared__ float red[256];

    int b  = blockIdx.y;
    int i0 = blockIdx.x;
    int t  = threadIdx.x;
    int w  = t >> 6, v = t & 63;

    const float* xb = x + (((size_t)b * 4096 + (size_t)i0 * 256) << 6);

    fz0[t] = ws[OFF_FZ0 + b * 256 + t];
    fz1[t] = ws[OFF_FZ1 + b * 256 + t];
    fz2[t] = ws[OFF_FZ2 + b * 256 + t];
    if (t < 16) {
        fx0[t] = ws[OFF_FX0 + b * 16 + t];
        fx1[t] = ws[OFF_FX1 + b * 16 + t];
        fx2[t] = ws[OFF_FX2 + b * 16 + t];
    }
    if (t < 192) {
        int ax = t >> 6, o = t & 63;
        int bit = 4 >> ax;
        Ctab[ax][o] = (unsigned char)S_of(S_of(o) ^ bit);
    }
    __syncthreads();                          // flags + Ctab ready

    {   // maskcode per site (j0*16+k0)
        int j0 = t >> 4, k0 = t & 15;
        unsigned m = (unsigned)fz0[k0 * 16 + j0]
                   | ((unsigned)fx0[k0] << 1)
                   | ((unsigned)fz1[i0 * 16 + k0] << 2)
                   | ((unsigned)fx1[i0] << 3)
                   | ((unsigned)fz2[j0 * 16 + i0] << 4)
                   | ((unsigned)fx2[j0] << 5);
        mArr[t] = (unsigned char)m;
    }
    for (int idx = t; idx < 4096; idx += 256) {
        int m = idx >> 6, vv = idx & 63;
        int src = vv;
        if (m & 32) src ^= 4;
        if (m & 16) src = Ctab[2][src];
        if (m & 8)  src ^= 2;
        if (m & 4)  src = Ctab[1][src];
        if (m & 2)  src ^= 1;
        if (m & 1)  src = Ctab[0][src];
        T[idx] = (unsigned char)src;
    }
    __syncthreads();                          // T + mArr ready

    // wave w streams sites [w*64, w*64+64); lane v accumulates output elem v.
    const unsigned char* Tv = T + v;
    int sbase = w * 64;
    float acc0 = 0.f, acc1 = 0.f;
#pragma unroll 16
    for (int s = 0; s < 64; s += 2) {
        int m0   = mArr[sbase + s];
        int m1   = mArr[sbase + s + 1];
        int src0 = Tv[m0 << 6];
        int src1 = Tv[m1 << 6];
        acc0 += __builtin_nontemporal_load(&xb[((sbase + s) << 6) | src0]);
        acc1 += __builtin_nontemporal_load(&xb[((sbase + s + 1) << 6) | src1]);
    }

    red[t] = acc0 + acc1;
    __syncthreads();
    if (t < 64) {
        float s4 = red[t] + red[t + 64] + red[t + 128] + red[t + 192];
        atomicAdd(out + b * 64 + t, s4 * (1.0f / 4096.0f));
    }
}

extern "C" void kernel_launch(void* const* d_in, const int* in_sizes, int n_in,
                              void* d_out, int out_size, void* d_ws, size_t ws_size,
                              hipStream_t stream) {
    const float* x   = (const float*)d_in[0];
    const int*   syn = (const int*)d_in[1];
    float* out = (float*)d_out;
    unsigned char* ws = (unsigned char*)d_ws;

    k_flags<<<dim3(BATCH, 6), 256, 0, stream>>>(syn, ws, out);
    k_main<<<dim3(16, BATCH), 256, 0, stream>>>(x, ws, out);
}

// Round 3
// 185.986 us; speedup vs baseline: 1.0786x; 1.0093x over previous
//
#include <hip/hip_runtime.h>
#include <stdint.h>

#define BATCH 128

// ws byte offsets
#define OFF_FZ0 0
#define OFF_FZ1 (OFF_FZ0 + BATCH * 256)
#define OFF_FZ2 (OFF_FZ1 + BATCH * 256)
#define OFF_FX0 (OFF_FZ2 + BATCH * 256)
#define OFF_FX1 (OFF_FX0 + BATCH * 16)
#define OFF_FX2 (OFF_FX1 + BATCH * 16)
#define OFF_T   (OFF_FX2 + BATCH * 16)   // 4 KB global T table (input-independent)

// ---- permutation algebra ----------------------------------------------------
__device__ __forceinline__ int A_of(int o) {
    return ((o & 7) << 3) | (((o >> 3) & 1) << 2) | (((o >> 4) & 1) << 1) | ((o >> 5) & 1);
}
__device__ __forceinline__ int S_of(int o) {
    const unsigned P = (0u) | (6u << 3) | (2u << 6) | (4u << 9) | (3u << 12) |
                       (5u << 15) | (1u << 18) | (7u << 21);
    int s = (int)((P >> (3 * (o >> 3))) & 7u);
    return A_of((s << 3) | (o & 7));
}

__device__ __forceinline__ unsigned flag16(const unsigned char* r, int pos) {
    unsigned f;
    if (pos == 0) {
        f = 0;
#pragma unroll
        for (int w = 0; w < 16; ++w) f ^= r[w];
    } else {
        f = r[0];
        for (int w = 17 - pos; w <= 15; ++w) f ^= r[w];
    }
    return f & 1u;
}

// ---- kernel 1: per-batch syndrome parity flags, 7-way job-parallel ---------
// grid (BATCH, 7). Job 0 also zeroes this batch's 64 output floats (replaces
// hipMemsetAsync). Job 6 (b==0 only) builds the input-independent T[64][64]
// permutation table into ws so k_main blocks skip the per-block table build.
__global__ __launch_bounds__(256) void k_flags(const int* __restrict__ syn,
                                               unsigned char* __restrict__ ws,
                                               float* __restrict__ out) {
    int b = blockIdx.x, job = blockIdx.y, t = threadIdx.x;
    int dhi = t >> 4, dlo = t & 15;
    const int* base = syn + (size_t)b * 16384;
    __shared__ unsigned char sp[256];
    __shared__ unsigned char g[16];
    __shared__ unsigned char Ctab[3][64];
    unsigned p = 0;

    if (job == 0) {                       // fz0 from z, parity over d1 (+ out zero)
        if (t < 64) out[b * 64 + t] = 0.0f;
        const int* z = base;
#pragma unroll
        for (int d1 = 0; d1 < 16; ++d1) p ^= (unsigned)z[d1 * 256 + t];
        sp[t] = p & 1;
        __syncthreads();
        ws[OFF_FZ0 + b * 256 + t] = (unsigned char)flag16(&sp[dhi * 16], dlo);
    } else if (job == 1) {                // fz1 from z, parity over d2
        const int* z = base;
#pragma unroll
        for (int d2 = 0; d2 < 16; ++d2) p ^= (unsigned)z[dhi * 256 + d2 * 16 + dlo];
        sp[t] = p & 1;
        __syncthreads();
        ws[OFF_FZ1 + b * 256 + t] = (unsigned char)flag16(&sp[dhi * 16], dlo);
    } else if (job == 2) {                // fz2 from z, parity over d3
        const int* z = base;
#pragma unroll
        for (int d3 = 0; d3 < 16; ++d3) p ^= (unsigned)z[dhi * 256 + dlo * 16 + d3];
        sp[t] = p & 1;
        __syncthreads();
        ws[OFF_FZ2 + b * 256 + t] = (unsigned char)flag16(&sp[dhi * 16], dlo);
    } else if (job == 3) {                // fx0 from x0
        const int* x0 = base + 4096;
#pragma unroll
        for (int d1 = 0; d1 < 16; ++d1) p ^= (unsigned)x0[d1 * 256 + t];
        sp[t] = p & 1;                    // t = (d2,d3)
        __syncthreads();
        if (t < 16) {
            unsigned q = 0;
            for (int d2 = 0; d2 < 16; ++d2) q ^= sp[d2 * 16 + t];
            g[(t + 1) & 15] = q & 1;      // roll shift 1
        }
        __syncthreads();
        if (t < 16) ws[OFF_FX0 + b * 16 + t] = (unsigned char)flag16(g, t);
    } else if (job == 4) {                // fx1 from x1
        const int* x1 = base + 8192;
#pragma unroll
        for (int d3 = 0; d3 < 16; ++d3) p ^= (unsigned)x1[dhi * 256 + dlo * 16 + d3];
        sp[t] = p & 1;                    // t = (d1,d2)
        __syncthreads();
        if (t < 16) {
            unsigned q = 0;
            for (int d2 = 0; d2 < 16; ++d2) q ^= sp[t * 16 + d2];
            g[t] = q & 1;
        }
        __syncthreads();
        if (t < 16) ws[OFF_FX1 + b * 16 + t] = (unsigned char)flag16(g, t);
    } else if (job == 5) {                // fx2 from x2
        const int* x2 = base + 12288;
#pragma unroll
        for (int d3 = 0; d3 < 16; ++d3) p ^= (unsigned)x2[dhi * 256 + dlo * 16 + d3];
        sp[t] = p & 1;                    // t = (d1,d2)
        __syncthreads();
        if (t < 16) {
            unsigned q = 0;
            for (int d1 = 0; d1 < 16; ++d1) q ^= sp[d1 * 16 + t];
            g[t] = q & 1;
        }
        __syncthreads();
        if (t < 16) ws[OFF_FX2 + b * 16 + t] = (unsigned char)flag16(g, t);
    } else {                              // job 6: build global T table (b==0 only)
        if (b != 0) return;
        if (t < 192) {
            int ax = t >> 6, o = t & 63;
            int bit = 4 >> ax;
            Ctab[ax][o] = (unsigned char)S_of(S_of(o) ^ bit);
        }
        __syncthreads();
        for (int idx = t; idx < 4096; idx += 256) {
            int m = idx >> 6, vv = idx & 63;
            int src = vv;
            if (m & 32) src ^= 4;
            if (m & 16) src = Ctab[2][src];
            if (m & 8)  src ^= 2;
            if (m & 4)  src = Ctab[1][src];
            if (m & 2)  src ^= 1;
            if (m & 1)  src = Ctab[0][src];
            ws[OFF_T + idx] = (unsigned char)src;
        }
    }
}

// ---- kernel 2: direct-global streaming with permuted addresses -------------
// Permuted per-lane dword reads inside one 256 B-aligned site row touch the
// same 4 cache lines as a linear read. Nontemporal loads keep single-use x
// out of L2/L3 (protects the co-timed harness fills). Preamble is now a
// single barrier: flags + T staged to LDS, then masks built wave-locally
// (mArr[t] is written and read only within wave t>>6).
__global__ __launch_bounds__(256) void k_main(const float* __restrict__ x,
                                              const unsigned char* __restrict__ ws,
                                              float* __restrict__ out) {
    __shared__ unsigned char T[4096];         // T[m][v] = source element
    __shared__ unsigned char fz0[256], fz1[256], fz2[256];
    __shared__ unsigned char fx0[16], fx1[16], fx2[16];
    __shared__ unsigned char mArr[256];
    __shared__ float red[256];

    int b  = blockIdx.y;
    int i0 = blockIdx.x;
    int t  = threadIdx.x;
    int w  = t >> 6, v = t & 63;

    const float* xb = x + (((size_t)b * 4096 + (size_t)i0 * 256) << 6);

    // stage T (4 KB, one uint4 per thread) and flags; single barrier below
    ((uint4*)T)[t] = ((const uint4*)(ws + OFF_T))[t];
    fz0[t] = ws[OFF_FZ0 + b * 256 + t];
    fz1[t] = ws[OFF_FZ1 + b * 256 + t];
    fz2[t] = ws[OFF_FZ2 + b * 256 + t];
    if (t < 16) {
        fx0[t] = ws[OFF_FX0 + b * 16 + t];
        fx1[t] = ws[OFF_FX1 + b * 16 + t];
        fx2[t] = ws[OFF_FX2 + b * 16 + t];
    }
    __syncthreads();                          // flags + T ready

    {   // maskcode per site (j0*16+k0) — wave-local write/read, no barrier
        int j0 = t >> 4, k0 = t & 15;
        unsigned m = (unsigned)fz0[k0 * 16 + j0]
                   | ((unsigned)fx0[k0] << 1)
                   | ((unsigned)fz1[i0 * 16 + k0] << 2)
                   | ((unsigned)fx1[i0] << 3)
                   | ((unsigned)fz2[j0 * 16 + i0] << 4)
                   | ((unsigned)fx2[j0] << 5);
        mArr[t] = (unsigned char)m;
    }

    // wave w streams sites [w*64, w*64+64); lane v accumulates output elem v.
    const unsigned char* Tv = T + v;
    int sbase = w * 64;
    float acc0 = 0.f, acc1 = 0.f;
#pragma unroll 16
    for (int s = 0; s < 64; s += 2) {
        int m0   = mArr[sbase + s];
        int m1   = mArr[sbase + s + 1];
        int src0 = Tv[m0 << 6];
        int src1 = Tv[m1 << 6];
        acc0 += __builtin_nontemporal_load(&xb[((sbase + s) << 6) | src0]);
        acc1 += __builtin_nontemporal_load(&xb[((sbase + s + 1) << 6) | src1]);
    }

    red[t] = acc0 + acc1;
    __syncthreads();
    if (t < 64) {
        float s4 = red[t] + red[t + 64] + red[t + 128] + red[t + 192];
        atomicAdd(out + b * 64 + t, s4 * (1.0f / 4096.0f));
    }
}

extern "C" void kernel_launch(void* const* d_in, const int* in_sizes, int n_in,
                              void* d_out, int out_size, void* d_ws, size_t ws_size,
                              hipStream_t stream) {
    const float* x   = (const float*)d_in[0];
    const int*   syn = (const int*)d_in[1];
    float* out = (float*)d_out;
    unsigned char* ws = (unsigned char*)d_ws;

    k_flags<<<dim3(BATCH, 7), 256, 0, stream>>>(syn, ws, out);
    k_main<<<dim3(16, BATCH), 256, 0, stream>>>(x, ws, out);
}